// Round 1
// baseline (292.940 us; speedup 1.0000x reference)
//
#include <hip/hip_runtime.h>
#include <hip/hip_fp16.h>

#define B_ROWS 4096
#define NTOT   8192
#define D0     256
#define D1     64
#define KDIM   320

typedef _Float16 half_t;
typedef __attribute__((ext_vector_type(8))) _Float16 half8;
typedef __attribute__((ext_vector_type(4))) _Float16 half4;
typedef __attribute__((ext_vector_type(4))) float f32x4;

// workspace layout (bytes)
#define OFF_ACC   0        // double
#define OFF_SS0   8        // double
#define OFF_SS1   16       // double
#define OFF_F0    24       // 256 doubles
#define OFF_F1    2072     // 64 doubles
#define OFF_GAM   2592     // 4 floats: g0,g1,sqrt(g0),sqrt(g1)
#define OFF_SQ0   2624     // 8192 floats
#define OFF_SQ1   35392    // 8192 floats
#define OFF_R     68160    // 8192 floats
#define OFF_PHI   133696   // 8192*320 halfs = 5242880 B

__device__ __forceinline__ void load_lds16(const void* g, void* l) {
    __builtin_amdgcn_global_load_lds(
        (const __attribute__((address_space(1))) void*)g,
        (__attribute__((address_space(3))) void*)l, 16, 0, 0);
}

// ---------------- K1: per-row sum of squares --------------------------------
__global__ __launch_bounds__(256) void k_rowsq(
    const float* __restrict__ s0, const float* __restrict__ s1,
    const float* __restrict__ t0, const float* __restrict__ t1,
    float* __restrict__ sq0, float* __restrict__ sq1,
    double* __restrict__ ssq0, double* __restrict__ ssq1) {
    int wv = threadIdx.x >> 6, lane = threadIdx.x & 63;
    int row = blockIdx.x * 4 + wv;
    const float* b0 = (row < B_ROWS) ? s0 + (size_t)row * D0 : t0 + (size_t)(row - B_ROWS) * D0;
    const float* b1 = (row < B_ROWS) ? s1 + (size_t)row * D1 : t1 + (size_t)(row - B_ROWS) * D1;
    f32x4 v = *(const f32x4*)(b0 + lane * 4);
    float p0 = v.x * v.x + v.y * v.y + v.z * v.z + v.w * v.w;
    float w = b1[lane];
    float p1 = w * w;
    #pragma unroll
    for (int o = 32; o; o >>= 1) { p0 += __shfl_xor(p0, o, 64); p1 += __shfl_xor(p1, o, 64); }
    if (lane == 0) {
        sq0[row] = p0; sq1[row] = p1;
        atomicAdd(ssq0, (double)p0);
        atomicAdd(ssq1, (double)p1);
    }
}

// ---------------- K2: per-column feature sums -------------------------------
__global__ __launch_bounds__(256) void k_colsum(
    const float* __restrict__ s0, const float* __restrict__ s1,
    const float* __restrict__ t0, const float* __restrict__ t1,
    double* __restrict__ F0, double* __restrict__ F1) {
    int t = threadIdx.x;
    int rb = blockIdx.x * 128;
    float sum0 = 0.f;
    for (int r = 0; r < 128; ++r) {
        int row = rb + r;
        const float* b0 = (row < B_ROWS) ? s0 + (size_t)row * D0 : t0 + (size_t)(row - B_ROWS) * D0;
        sum0 += b0[t];
    }
    atomicAdd(&F0[t], (double)sum0);
    if (t < D1) {
        float sum1 = 0.f;
        for (int r = 0; r < 128; ++r) {
            int row = rb + r;
            const float* b1 = (row < B_ROWS) ? s1 + (size_t)row * D1 : t1 + (size_t)(row - B_ROWS) * D1;
            sum1 += b1[t];
        }
        atomicAdd(&F1[t], (double)sum1);
    }
}

// ---------------- K3: gamma ---------------------------------------------------
__global__ void k_gamma(const double* __restrict__ ssq0, const double* __restrict__ ssq1,
                        const double* __restrict__ F0, const double* __restrict__ F1,
                        float* __restrict__ gam) {
    if (threadIdx.x == 0 && blockIdx.x == 0) {
        double n = (double)NTOT;
        double nf0 = 0.0, nf1 = 0.0;
        for (int k = 0; k < D0; ++k) nf0 += F0[k] * F0[k];
        for (int k = 0; k < D1; ++k) nf1 += F1[k] * F1[k];
        double den0 = 2.0 * n * (*ssq0) - 2.0 * nf0;
        double den1 = 2.0 * n * (*ssq1) - 2.0 * nf1;
        double g0 = (n * n - n) / den0;
        double g1 = (n * n - n) / den1;
        gam[0] = (float)g0; gam[1] = (float)g1;
        gam[2] = (float)sqrt(g0); gam[3] = (float)sqrt(g1);
    }
}

// ---------------- K4: pack scaled fp16 features + r vector -------------------
__global__ __launch_bounds__(256) void k_pack(
    const float* __restrict__ s0, const float* __restrict__ s1,
    const float* __restrict__ t0, const float* __restrict__ t1,
    const float* __restrict__ sq0, const float* __restrict__ sq1,
    const float* __restrict__ gam, half_t* __restrict__ phi, float* __restrict__ rvec) {
    int wv = threadIdx.x >> 6, lane = threadIdx.x & 63;
    int row = blockIdx.x * 4 + wv;
    float g0 = gam[0], g1 = gam[1], sg0 = gam[2], sg1 = gam[3];
    const float* b0 = (row < B_ROWS) ? s0 + (size_t)row * D0 : t0 + (size_t)(row - B_ROWS) * D0;
    const float* b1 = (row < B_ROWS) ? s1 + (size_t)row * D1 : t1 + (size_t)(row - B_ROWS) * D1;
    half_t* pr = phi + (size_t)row * KDIM;
    f32x4 v = *(const f32x4*)(b0 + lane * 4);
    half4 h;
    h.x = (half_t)(v.x * sg0); h.y = (half_t)(v.y * sg0);
    h.z = (half_t)(v.z * sg0); h.w = (half_t)(v.w * sg0);
    *(half4*)(pr + lane * 4) = h;
    pr[D0 + lane] = (half_t)(b1[lane] * sg1);
    if (lane == 0) rvec[row] = g0 * sq0[row] + g1 * sq1[row];
}

// ---------------- K5: main fused Gram+exp+reduce kernel ----------------------
// 128x128 tile, 4 waves (each 64x64), BK=64, K=320, upper-triangle tiles only.
__global__ __launch_bounds__(256) void k_mmd(
    const half_t* __restrict__ phi, const float* __restrict__ rvec,
    double* __restrict__ acc) {
    int J = blockIdx.x, I = blockIdx.y;
    if (I > J) return;

    __shared__ half_t As[128 * 64];
    __shared__ half_t Bs[128 * 64];
    __shared__ float rIl[128], rJl[128];
    __shared__ float wsum[4];

    int tid = threadIdx.x, wv = tid >> 6, lane = tid & 63;
    int wr = wv >> 1, wc = wv & 1;
    int rgrp = lane >> 4, rlow = lane & 15;

    if (tid < 128) rIl[tid] = rvec[I * 128 + tid];
    else           rJl[tid - 128] = rvec[J * 128 + (tid - 128)];

    f32x4 acc_[4][4] = {};
    const int rowA = I * 128, rowB = J * 128;

    for (int ks = 0; ks < 5; ++ks) {
        // stage A and B K-slabs into LDS, source pre-swizzled so that
        // LDS slot (r, s) holds global col16 (s ^ (r&7))
        #pragma unroll
        for (int it = 0; it < 4; ++it) {
            int rs = wv * 32 + it * 8;
            int r = rs + (lane >> 3);
            int slot = lane & 7;
            int gcol = ks * 64 + ((slot ^ (r & 7)) << 3);
            const half_t* gpA = phi + (size_t)(rowA + r) * KDIM + gcol;
            const half_t* gpB = phi + (size_t)(rowB + r) * KDIM + gcol;
            load_lds16(gpA, &As[rs * 64]);
            load_lds16(gpB, &Bs[rs * 64]);
        }
        __syncthreads();

        half8 af[4][2], bf[4][2];
        #pragma unroll
        for (int m = 0; m < 4; ++m) {
            int row = wr * 64 + m * 16 + rlow;
            #pragma unroll
            for (int kk = 0; kk < 2; ++kk) {
                int slot = (kk * 4 + rgrp) ^ (row & 7);
                af[m][kk] = *(const half8*)&As[row * 64 + slot * 8];
            }
        }
        #pragma unroll
        for (int n = 0; n < 4; ++n) {
            int col = wc * 64 + n * 16 + rlow;
            #pragma unroll
            for (int kk = 0; kk < 2; ++kk) {
                int slot = (kk * 4 + rgrp) ^ (col & 7);
                bf[n][kk] = *(const half8*)&Bs[col * 64 + slot * 8];
            }
        }
        #pragma unroll
        for (int m = 0; m < 4; ++m)
            #pragma unroll
            for (int n = 0; n < 4; ++n)
                #pragma unroll
                for (int kk = 0; kk < 2; ++kk)
                    acc_[m][n] = __builtin_amdgcn_mfma_f32_16x16x32_f16(
                        af[m][kk], bf[n][kk], acc_[m][n], 0, 0, 0);
        __syncthreads();
    }

    // epilogue: K_ij = exp(2*dot - r_i - r_j); sum tile
    float psum = 0.f;
    #pragma unroll
    for (int m = 0; m < 4; ++m) {
        float ri[4];
        #pragma unroll
        for (int j = 0; j < 4; ++j) ri[j] = rIl[wr * 64 + m * 16 + rgrp * 4 + j];
        #pragma unroll
        for (int n = 0; n < 4; ++n) {
            float rj = rJl[wc * 64 + n * 16 + rlow];
            f32x4 a = acc_[m][n];
            psum += __expf(2.f * a.x - ri[0] - rj);
            psum += __expf(2.f * a.y - ri[1] - rj);
            psum += __expf(2.f * a.z - ri[2] - rj);
            psum += __expf(2.f * a.w - ri[3] - rj);
        }
    }
    #pragma unroll
    for (int o = 32; o; o >>= 1) psum += __shfl_xor(psum, o, 64);
    if (lane == 0) wsum[wv] = psum;
    __syncthreads();
    if (tid == 0) {
        float bs = wsum[0] + wsum[1] + wsum[2] + wsum[3];
        double sgn = ((I < 32) == (J < 32)) ? 1.0 : -1.0;
        double fac = (I == J) ? 1.0 : 2.0;
        atomicAdd(acc, sgn * fac * (double)bs);
    }
}

// ---------------- K6: finalize ----------------------------------------------
__global__ void k_final(const double* __restrict__ acc, float* __restrict__ out) {
    if (threadIdx.x == 0 && blockIdx.x == 0)
        out[0] = (float)(acc[0] / ((double)B_ROWS * (double)B_ROWS));
}

extern "C" void kernel_launch(void* const* d_in, const int* in_sizes, int n_in,
                              void* d_out, int out_size, void* d_ws, size_t ws_size,
                              hipStream_t stream) {
    const float* s0 = (const float*)d_in[0];
    const float* s1 = (const float*)d_in[1];
    const float* t0 = (const float*)d_in[2];
    const float* t1 = (const float*)d_in[3];
    char* ws = (char*)d_ws;
    double* acc  = (double*)(ws + OFF_ACC);
    double* ssq0 = (double*)(ws + OFF_SS0);
    double* ssq1 = (double*)(ws + OFF_SS1);
    double* F0   = (double*)(ws + OFF_F0);
    double* F1   = (double*)(ws + OFF_F1);
    float*  gam  = (float*)(ws + OFF_GAM);
    float*  sq0  = (float*)(ws + OFF_SQ0);
    float*  sq1  = (float*)(ws + OFF_SQ1);
    float*  rvec = (float*)(ws + OFF_R);
    half_t* phi  = (half_t*)(ws + OFF_PHI);

    hipMemsetAsync(d_ws, 0, OFF_GAM + 16, stream);
    k_rowsq<<<2048, 256, 0, stream>>>(s0, s1, t0, t1, sq0, sq1, ssq0, ssq1);
    k_colsum<<<64, 256, 0, stream>>>(s0, s1, t0, t1, F0, F1);
    k_gamma<<<1, 64, 0, stream>>>(ssq0, ssq1, F0, F1, gam);
    k_pack<<<2048, 256, 0, stream>>>(s0, s1, t0, t1, sq0, sq1, gam, phi, rvec);
    k_mmd<<<dim3(64, 64), 256, 0, stream>>>(phi, rvec, acc);
    k_final<<<1, 64, 0, stream>>>(acc, (float*)d_out);
}

// Round 2
// 93.084 us; speedup vs baseline: 3.1470x; 3.1470x over previous
//
#include <hip/hip_runtime.h>
#include <hip/hip_fp16.h>

#define B_ROWS 4096
#define NTOT   8192
#define D0     256
#define D1     64
#define KDIM   320
#define NCB    128   // colsum blocks (64 rows each)

typedef _Float16 half_t;
typedef __attribute__((ext_vector_type(8))) _Float16 half8;
typedef __attribute__((ext_vector_type(4))) _Float16 half4;
typedef __attribute__((ext_vector_type(4))) float f32x4;

// workspace layout (bytes)
#define OFF_GAM   0        // 4 floats: g0,g1,sqrt(g0),sqrt(g1)
#define OFF_SQ0   16       // 8192 floats
#define OFF_SQ1   32784    // 8192 floats
#define OFF_R     65552    // 8192 floats
#define OFF_P0    98320    // 128*256 floats
#define OFF_P1    229392   // 128*64 floats
#define OFF_BSUM  262160   // 4096 doubles
#define OFF_PHI   294928   // 8192*320 halfs

__device__ __forceinline__ void load_lds16(const void* g, void* l) {
    __builtin_amdgcn_global_load_lds(
        (const __attribute__((address_space(1))) void*)g,
        (__attribute__((address_space(3))) void*)l, 16, 0, 0);
}

// ---------------- K1: per-row sum of squares (no atomics) -------------------
__global__ __launch_bounds__(256) void k_rowsq(
    const float* __restrict__ s0, const float* __restrict__ s1,
    const float* __restrict__ t0, const float* __restrict__ t1,
    float* __restrict__ sq0, float* __restrict__ sq1) {
    int wv = threadIdx.x >> 6, lane = threadIdx.x & 63;
    int row = blockIdx.x * 4 + wv;
    const float* b0 = (row < B_ROWS) ? s0 + (size_t)row * D0 : t0 + (size_t)(row - B_ROWS) * D0;
    const float* b1 = (row < B_ROWS) ? s1 + (size_t)row * D1 : t1 + (size_t)(row - B_ROWS) * D1;
    f32x4 v = *(const f32x4*)(b0 + lane * 4);
    float p0 = v.x * v.x + v.y * v.y + v.z * v.z + v.w * v.w;
    float w = b1[lane];
    float p1 = w * w;
    #pragma unroll
    for (int o = 32; o; o >>= 1) { p0 += __shfl_xor(p0, o, 64); p1 += __shfl_xor(p1, o, 64); }
    if (lane == 0) { sq0[row] = p0; sq1[row] = p1; }
}

// ---------------- K2: partial column sums (no atomics) ----------------------
__global__ __launch_bounds__(256) void k_colsum(
    const float* __restrict__ s0, const float* __restrict__ s1,
    const float* __restrict__ t0, const float* __restrict__ t1,
    float* __restrict__ part0, float* __restrict__ part1) {
    int t = threadIdx.x;
    int rb = blockIdx.x * 64;
    float sum0 = 0.f;
    for (int r = 0; r < 64; ++r) {
        int row = rb + r;
        const float* b0 = (row < B_ROWS) ? s0 + (size_t)row * D0 : t0 + (size_t)(row - B_ROWS) * D0;
        sum0 += b0[t];
    }
    part0[blockIdx.x * D0 + t] = sum0;
    if (t < D1) {
        float sum1 = 0.f;
        for (int r = 0; r < 64; ++r) {
            int row = rb + r;
            const float* b1 = (row < B_ROWS) ? s1 + (size_t)row * D1 : t1 + (size_t)(row - B_ROWS) * D1;
            sum1 += b1[t];
        }
        part1[blockIdx.x * D1 + t] = sum1;
    }
}

// ---------------- K3: gamma (single block, fp64 reduce) ----------------------
__global__ __launch_bounds__(256) void k_gamma(
    const float* __restrict__ sq0, const float* __restrict__ sq1,
    const float* __restrict__ part0, const float* __restrict__ part1,
    float* __restrict__ gam) {
    __shared__ double sh[4][4];
    int t = threadIdx.x, wv = t >> 6, lane = t & 63;

    double ssq0 = 0.0, ssq1 = 0.0;
    for (int i = t; i < NTOT; i += 256) { ssq0 += (double)sq0[i]; ssq1 += (double)sq1[i]; }

    double F0t = 0.0;
    for (int b = 0; b < NCB; ++b) F0t += (double)part0[b * D0 + t];
    double nf0 = F0t * F0t;

    double nf1 = 0.0;
    if (t < D1) {
        double F1t = 0.0;
        for (int b = 0; b < NCB; ++b) F1t += (double)part1[b * D1 + t];
        nf1 = F1t * F1t;
    }

    #pragma unroll
    for (int o = 32; o; o >>= 1) {
        ssq0 += __shfl_xor(ssq0, o, 64);
        ssq1 += __shfl_xor(ssq1, o, 64);
        nf0  += __shfl_xor(nf0, o, 64);
        nf1  += __shfl_xor(nf1, o, 64);
    }
    if (lane == 0) { sh[wv][0] = ssq0; sh[wv][1] = ssq1; sh[wv][2] = nf0; sh[wv][3] = nf1; }
    __syncthreads();
    if (t == 0) {
        double a0 = 0, a1 = 0, a2 = 0, a3 = 0;
        for (int w = 0; w < 4; ++w) { a0 += sh[w][0]; a1 += sh[w][1]; a2 += sh[w][2]; a3 += sh[w][3]; }
        double n = (double)NTOT;
        double g0 = (n * n - n) / (2.0 * n * a0 - 2.0 * a2);
        double g1 = (n * n - n) / (2.0 * n * a1 - 2.0 * a3);
        gam[0] = (float)g0; gam[1] = (float)g1;
        gam[2] = (float)sqrt(g0); gam[3] = (float)sqrt(g1);
    }
}

// ---------------- K4: pack scaled fp16 features + r vector -------------------
__global__ __launch_bounds__(256) void k_pack(
    const float* __restrict__ s0, const float* __restrict__ s1,
    const float* __restrict__ t0, const float* __restrict__ t1,
    const float* __restrict__ sq0, const float* __restrict__ sq1,
    const float* __restrict__ gam, half_t* __restrict__ phi, float* __restrict__ rvec) {
    int wv = threadIdx.x >> 6, lane = threadIdx.x & 63;
    int row = blockIdx.x * 4 + wv;
    float g0 = gam[0], g1 = gam[1], sg0 = gam[2], sg1 = gam[3];
    const float* b0 = (row < B_ROWS) ? s0 + (size_t)row * D0 : t0 + (size_t)(row - B_ROWS) * D0;
    const float* b1 = (row < B_ROWS) ? s1 + (size_t)row * D1 : t1 + (size_t)(row - B_ROWS) * D1;
    half_t* pr = phi + (size_t)row * KDIM;
    f32x4 v = *(const f32x4*)(b0 + lane * 4);
    half4 h;
    h.x = (half_t)(v.x * sg0); h.y = (half_t)(v.y * sg0);
    h.z = (half_t)(v.z * sg0); h.w = (half_t)(v.w * sg0);
    *(half4*)(pr + lane * 4) = h;
    pr[D0 + lane] = (half_t)(b1[lane] * sg1);
    if (lane == 0) rvec[row] = g0 * sq0[row] + g1 * sq1[row];
}

// ---------------- K5: main fused Gram+exp+reduce kernel ----------------------
// 128x128 tile, 4 waves (each 64x64), BK=64, K=320, upper-triangle tiles only.
__global__ __launch_bounds__(256) void k_mmd(
    const half_t* __restrict__ phi, const float* __restrict__ rvec,
    double* __restrict__ blocksum) {
    int J = blockIdx.x, I = blockIdx.y;
    int bix = I * 64 + J;
    int tid = threadIdx.x, wv = tid >> 6, lane = tid & 63;
    if (I > J) { if (tid == 0) blocksum[bix] = 0.0; return; }

    __shared__ half_t As[128 * 64];
    __shared__ half_t Bs[128 * 64];
    __shared__ float rIl[128], rJl[128];
    __shared__ float wsum[4];

    int wr = wv >> 1, wc = wv & 1;
    int rgrp = lane >> 4, rlow = lane & 15;

    if (tid < 128) rIl[tid] = rvec[I * 128 + tid];
    else           rJl[tid - 128] = rvec[J * 128 + (tid - 128)];

    f32x4 acc_[4][4] = {};
    const int rowA = I * 128, rowB = J * 128;

    for (int ks = 0; ks < 5; ++ks) {
        // stage A and B K-slabs into LDS, source pre-swizzled so that
        // LDS slot (r, s) holds global col16 (s ^ (r&7))
        #pragma unroll
        for (int it = 0; it < 4; ++it) {
            int rs = wv * 32 + it * 8;
            int r = rs + (lane >> 3);
            int slot = lane & 7;
            int gcol = ks * 64 + ((slot ^ (r & 7)) << 3);
            const half_t* gpA = phi + (size_t)(rowA + r) * KDIM + gcol;
            const half_t* gpB = phi + (size_t)(rowB + r) * KDIM + gcol;
            load_lds16(gpA, &As[rs * 64]);
            load_lds16(gpB, &Bs[rs * 64]);
        }
        __syncthreads();

        half8 af[4][2], bf[4][2];
        #pragma unroll
        for (int m = 0; m < 4; ++m) {
            int row = wr * 64 + m * 16 + rlow;
            #pragma unroll
            for (int kk = 0; kk < 2; ++kk) {
                int slot = (kk * 4 + rgrp) ^ (row & 7);
                af[m][kk] = *(const half8*)&As[row * 64 + slot * 8];
            }
        }
        #pragma unroll
        for (int n = 0; n < 4; ++n) {
            int col = wc * 64 + n * 16 + rlow;
            #pragma unroll
            for (int kk = 0; kk < 2; ++kk) {
                int slot = (kk * 4 + rgrp) ^ (col & 7);
                bf[n][kk] = *(const half8*)&Bs[col * 64 + slot * 8];
            }
        }
        #pragma unroll
        for (int m = 0; m < 4; ++m)
            #pragma unroll
            for (int n = 0; n < 4; ++n)
                #pragma unroll
                for (int kk = 0; kk < 2; ++kk)
                    acc_[m][n] = __builtin_amdgcn_mfma_f32_16x16x32_f16(
                        af[m][kk], bf[n][kk], acc_[m][n], 0, 0, 0);
        __syncthreads();
    }

    // epilogue: K_ij = exp(2*dot - r_i - r_j); sum tile
    float psum = 0.f;
    #pragma unroll
    for (int m = 0; m < 4; ++m) {
        float ri[4];
        #pragma unroll
        for (int j = 0; j < 4; ++j) ri[j] = rIl[wr * 64 + m * 16 + rgrp * 4 + j];
        #pragma unroll
        for (int n = 0; n < 4; ++n) {
            float rj = rJl[wc * 64 + n * 16 + rlow];
            f32x4 a = acc_[m][n];
            psum += __expf(2.f * a.x - ri[0] - rj);
            psum += __expf(2.f * a.y - ri[1] - rj);
            psum += __expf(2.f * a.z - ri[2] - rj);
            psum += __expf(2.f * a.w - ri[3] - rj);
        }
    }
    #pragma unroll
    for (int o = 32; o; o >>= 1) psum += __shfl_xor(psum, o, 64);
    if (lane == 0) wsum[wv] = psum;
    __syncthreads();
    if (tid == 0) {
        float bs = wsum[0] + wsum[1] + wsum[2] + wsum[3];
        double sgn = ((I < 32) == (J < 32)) ? 1.0 : -1.0;
        double fac = (I == J) ? 1.0 : 2.0;
        blocksum[bix] = sgn * fac * (double)bs;
    }
}

// ---------------- K6: finalize (reduce 4096 block sums) ----------------------
__global__ __launch_bounds__(256) void k_final(
    const double* __restrict__ blocksum, float* __restrict__ out) {
    __shared__ double sh[4];
    int t = threadIdx.x, wv = t >> 6, lane = t & 63;
    double s = 0.0;
    for (int i = t; i < 4096; i += 256) s += blocksum[i];
    #pragma unroll
    for (int o = 32; o; o >>= 1) s += __shfl_xor(s, o, 64);
    if (lane == 0) sh[wv] = s;
    __syncthreads();
    if (t == 0) {
        double tot = sh[0] + sh[1] + sh[2] + sh[3];
        out[0] = (float)(tot / ((double)B_ROWS * (double)B_ROWS));
    }
}

extern "C" void kernel_launch(void* const* d_in, const int* in_sizes, int n_in,
                              void* d_out, int out_size, void* d_ws, size_t ws_size,
                              hipStream_t stream) {
    const float* s0 = (const float*)d_in[0];
    const float* s1 = (const float*)d_in[1];
    const float* t0 = (const float*)d_in[2];
    const float* t1 = (const float*)d_in[3];
    char* ws = (char*)d_ws;
    float*  gam  = (float*)(ws + OFF_GAM);
    float*  sq0  = (float*)(ws + OFF_SQ0);
    float*  sq1  = (float*)(ws + OFF_SQ1);
    float*  rvec = (float*)(ws + OFF_R);
    float*  p0   = (float*)(ws + OFF_P0);
    float*  p1   = (float*)(ws + OFF_P1);
    double* bsum = (double*)(ws + OFF_BSUM);
    half_t* phi  = (half_t*)(ws + OFF_PHI);

    k_rowsq<<<2048, 256, 0, stream>>>(s0, s1, t0, t1, sq0, sq1);
    k_colsum<<<NCB, 256, 0, stream>>>(s0, s1, t0, t1, p0, p1);
    k_gamma<<<1, 256, 0, stream>>>(sq0, sq1, p0, p1, gam);
    k_pack<<<2048, 256, 0, stream>>>(s0, s1, t0, t1, sq0, sq1, gam, phi, rvec);
    k_mmd<<<dim3(64, 64), 256, 0, stream>>>(phi, rvec, bsum);
    k_final<<<1, 256, 0, stream>>>(bsum, (float*)d_out);
}

// Round 3
// 69.247 us; speedup vs baseline: 4.2303x; 1.3442x over previous
//
#include <hip/hip_runtime.h>
#include <hip/hip_fp16.h>
#include <hip/hip_fp8.h>

#define B_ROWS 4096
#define NTOT   8192
#define D0     256
#define D1     64
#define KDIM   320   // bytes per phi row (fp8)
#define NCB    128   // colsum blocks (64 rows each)
#define NTILE  64    // 8192 / 128
#define NTRI   2080  // NTILE*(NTILE+1)/2

typedef __attribute__((ext_vector_type(4))) float f32x4;

// workspace layout (bytes)
#define OFF_GAM   0        // 4 floats
#define OFF_SQ0   16       // 8192 floats
#define OFF_SQ1   32784    // 8192 floats
#define OFF_R     65552    // 8192 floats
#define OFF_P0    98320    // 128*256 floats
#define OFF_P1    229392   // 128*64 floats
#define OFF_BSUM  262160   // 2080 doubles
#define OFF_PHI   278800   // 8192*320 bytes (fp8), 16B aligned

__device__ __forceinline__ void load_lds16(const void* g, void* l) {
    __builtin_amdgcn_global_load_lds(
        (const __attribute__((address_space(1))) void*)g,
        (__attribute__((address_space(3))) void*)l, 16, 0, 0);
}

// ---------------- K1: per-row sum of squares (fp32, feeds gamma) ------------
__global__ __launch_bounds__(256) void k_rowsq(
    const float* __restrict__ s0, const float* __restrict__ s1,
    const float* __restrict__ t0, const float* __restrict__ t1,
    float* __restrict__ sq0, float* __restrict__ sq1) {
    int wv = threadIdx.x >> 6, lane = threadIdx.x & 63;
    int row = blockIdx.x * 4 + wv;
    const float* b0 = (row < B_ROWS) ? s0 + (size_t)row * D0 : t0 + (size_t)(row - B_ROWS) * D0;
    const float* b1 = (row < B_ROWS) ? s1 + (size_t)row * D1 : t1 + (size_t)(row - B_ROWS) * D1;
    f32x4 v = *(const f32x4*)(b0 + lane * 4);
    float p0 = v.x * v.x + v.y * v.y + v.z * v.z + v.w * v.w;
    float w = b1[lane];
    float p1 = w * w;
    #pragma unroll
    for (int o = 32; o; o >>= 1) { p0 += __shfl_xor(p0, o, 64); p1 += __shfl_xor(p1, o, 64); }
    if (lane == 0) { sq0[row] = p0; sq1[row] = p1; }
}

// ---------------- K2: partial column sums -----------------------------------
__global__ __launch_bounds__(256) void k_colsum(
    const float* __restrict__ s0, const float* __restrict__ s1,
    const float* __restrict__ t0, const float* __restrict__ t1,
    float* __restrict__ part0, float* __restrict__ part1) {
    int t = threadIdx.x;
    int rb = blockIdx.x * 64;
    float sum0 = 0.f;
    for (int r = 0; r < 64; ++r) {
        int row = rb + r;
        const float* b0 = (row < B_ROWS) ? s0 + (size_t)row * D0 : t0 + (size_t)(row - B_ROWS) * D0;
        sum0 += b0[t];
    }
    part0[blockIdx.x * D0 + t] = sum0;
    if (t < D1) {
        float sum1 = 0.f;
        for (int r = 0; r < 64; ++r) {
            int row = rb + r;
            const float* b1 = (row < B_ROWS) ? s1 + (size_t)row * D1 : t1 + (size_t)(row - B_ROWS) * D1;
            sum1 += b1[t];
        }
        part1[blockIdx.x * D1 + t] = sum1;
    }
}

// ---------------- K3: gamma (single block, fp64 reduce) ----------------------
__global__ __launch_bounds__(256) void k_gamma(
    const float* __restrict__ sq0, const float* __restrict__ sq1,
    const float* __restrict__ part0, const float* __restrict__ part1,
    float* __restrict__ gam) {
    __shared__ double sh[4][4];
    int t = threadIdx.x, wv = t >> 6, lane = t & 63;

    double ssq0 = 0.0, ssq1 = 0.0;
    for (int i = t; i < NTOT; i += 256) { ssq0 += (double)sq0[i]; ssq1 += (double)sq1[i]; }

    double F0t = 0.0;
    for (int b = 0; b < NCB; ++b) F0t += (double)part0[b * D0 + t];
    double nf0 = F0t * F0t;

    double nf1 = 0.0;
    if (t < D1) {
        double F1t = 0.0;
        for (int b = 0; b < NCB; ++b) F1t += (double)part1[b * D1 + t];
        nf1 = F1t * F1t;
    }

    #pragma unroll
    for (int o = 32; o; o >>= 1) {
        ssq0 += __shfl_xor(ssq0, o, 64);
        ssq1 += __shfl_xor(ssq1, o, 64);
        nf0  += __shfl_xor(nf0, o, 64);
        nf1  += __shfl_xor(nf1, o, 64);
    }
    if (lane == 0) { sh[wv][0] = ssq0; sh[wv][1] = ssq1; sh[wv][2] = nf0; sh[wv][3] = nf1; }
    __syncthreads();
    if (t == 0) {
        double a0 = 0, a1 = 0, a2 = 0, a3 = 0;
        for (int w = 0; w < 4; ++w) { a0 += sh[w][0]; a1 += sh[w][1]; a2 += sh[w][2]; a3 += sh[w][3]; }
        double n = (double)NTOT;
        double g0 = (n * n - n) / (2.0 * n * a0 - 2.0 * a2);
        double g1 = (n * n - n) / (2.0 * n * a1 - 2.0 * a3);
        gam[0] = (float)g0; gam[1] = (float)g1;
        gam[2] = (float)sqrt(g0); gam[3] = (float)sqrt(g1);
    }
}

// ---------------- K4: pack scaled fp8 features + r from quantized -----------
__global__ __launch_bounds__(256) void k_pack(
    const float* __restrict__ s0, const float* __restrict__ s1,
    const float* __restrict__ t0, const float* __restrict__ t1,
    const float* __restrict__ gam, unsigned char* __restrict__ phi,
    float* __restrict__ rvec) {
    int wv = threadIdx.x >> 6, lane = threadIdx.x & 63;
    int row = blockIdx.x * 4 + wv;
    float sg0 = gam[2], sg1 = gam[3];
    const float* b0 = (row < B_ROWS) ? s0 + (size_t)row * D0 : t0 + (size_t)(row - B_ROWS) * D0;
    const float* b1 = (row < B_ROWS) ? s1 + (size_t)row * D1 : t1 + (size_t)(row - B_ROWS) * D1;
    unsigned char* pr = phi + (size_t)row * KDIM;
    f32x4 v = *(const f32x4*)(b0 + lane * 4);
    __hip_fp8_e4m3 q0(v.x * sg0), q1(v.y * sg0), q2(v.z * sg0), q3(v.w * sg0);
    unsigned int word = (unsigned int)q0.__x | ((unsigned int)q1.__x << 8) |
                        ((unsigned int)q2.__x << 16) | ((unsigned int)q3.__x << 24);
    *(unsigned int*)(pr + lane * 4) = word;
    float f0 = (float)q0, f1 = (float)q1, f2 = (float)q2, f3 = (float)q3;
    float p = f0 * f0 + f1 * f1 + f2 * f2 + f3 * f3;
    __hip_fp8_e4m3 qd(b1[lane] * sg1);
    pr[D0 + lane] = qd.__x;
    float fd = (float)qd;
    p += fd * fd;
    #pragma unroll
    for (int o = 32; o; o >>= 1) p += __shfl_xor(p, o, 64);
    if (lane == 0) rvec[row] = p;   // r_i = ||phi_hat_i||^2 (exact wrt quantized)
}

// ---------------- K5: fused Gram+exp+reduce, fp8, 2-phase dbuf ---------------
// 128x128 tile, 4 waves (64x64 each), BK=64 fp8-elems, K=320, upper-tri grid.
__global__ __launch_bounds__(256) void k_mmd(
    const unsigned char* __restrict__ phi, const float* __restrict__ rvec,
    double* __restrict__ blocksum) {
    // triangular decode: block t -> (I,J), I<=J
    int t = blockIdx.x;
    int I = (int)((129.0f - sqrtf(16641.0f - 8.0f * (float)t)) * 0.5f);
    while ((129 * I - I * I) / 2 > t) --I;
    while ((129 * (I + 1) - (I + 1) * (I + 1)) / 2 <= t) ++I;
    int J = I + (t - (129 * I - I * I) / 2);

    __shared__ unsigned char As[2][8192];
    __shared__ unsigned char Bs[2][8192];
    __shared__ float rIl[128], rJl[128];
    __shared__ float wsum[4];

    int tid = threadIdx.x, wv = tid >> 6, lane = tid & 63;
    int wr = wv >> 1, wc = wv & 1;
    int rgrp = lane >> 4, rlow = lane & 15;
    const int rowA = I * 128, rowB = J * 128;

    if (tid < 128) rIl[tid] = rvec[rowA + tid];
    else           rJl[tid - 128] = rvec[rowB + (tid - 128)];

    // staging: LDS slot16 u at row r holds global col16 (u ^ ((r>>1)&3))
    int su = tid & 3;
    int sr0 = tid >> 2;      // 0..63
    #define STAGE(b, ks)                                                        \
        _Pragma("unroll")                                                       \
        for (int p = 0; p < 2; ++p) {                                           \
            int r = p * 64 + sr0;                                               \
            int gc = (ks) * 64 + ((su ^ ((r >> 1) & 3)) << 4);                  \
            load_lds16(phi + (size_t)(rowA + r) * KDIM + gc,                    \
                       &As[b][p * 4096 + wv * 1024]);                           \
            load_lds16(phi + (size_t)(rowB + r) * KDIM + gc,                    \
                       &Bs[b][p * 4096 + wv * 1024]);                           \
        }

    f32x4 acc_[4][4] = {};

    STAGE(0, 0);
    __syncthreads();

    int cur = 0;
    for (int ks = 0; ks < 5; ++ks) {
        if (ks < 4) { STAGE(cur ^ 1, ks + 1); }

        long af[4][2], bf[4][2];
        #pragma unroll
        for (int m = 0; m < 4; ++m) {
            int row = wr * 64 + m * 16 + rlow;
            #pragma unroll
            for (int kk = 0; kk < 2; ++kk) {
                int s16 = kk * 2 + (rgrp >> 1);
                int addr = row * 64 + ((s16 ^ ((row >> 1) & 3)) << 4) + (rgrp & 1) * 8;
                af[m][kk] = *(const long*)&As[cur][addr];
            }
        }
        #pragma unroll
        for (int n = 0; n < 4; ++n) {
            int col = wc * 64 + n * 16 + rlow;
            #pragma unroll
            for (int kk = 0; kk < 2; ++kk) {
                int s16 = kk * 2 + (rgrp >> 1);
                int addr = col * 64 + ((s16 ^ ((col >> 1) & 3)) << 4) + (rgrp & 1) * 8;
                bf[n][kk] = *(const long*)&Bs[cur][addr];
            }
        }
        #pragma unroll
        for (int m = 0; m < 4; ++m)
            #pragma unroll
            for (int n = 0; n < 4; ++n)
                #pragma unroll
                for (int kk = 0; kk < 2; ++kk)
                    acc_[m][n] = __builtin_amdgcn_mfma_f32_16x16x32_fp8_fp8(
                        af[m][kk], bf[n][kk], acc_[m][n], 0, 0, 0);
        __syncthreads();
        cur ^= 1;
    }

    // epilogue: K_ij = exp(2*dot - r_i - r_j) = exp(-||phi_i - phi_j||^2)
    float psum = 0.f;
    #pragma unroll
    for (int m = 0; m < 4; ++m) {
        float ri[4];
        #pragma unroll
        for (int j = 0; j < 4; ++j) ri[j] = rIl[wr * 64 + m * 16 + rgrp * 4 + j];
        #pragma unroll
        for (int n = 0; n < 4; ++n) {
            float rj = rJl[wc * 64 + n * 16 + rlow];
            f32x4 a = acc_[m][n];
            psum += __expf(2.f * a.x - ri[0] - rj);
            psum += __expf(2.f * a.y - ri[1] - rj);
            psum += __expf(2.f * a.z - ri[2] - rj);
            psum += __expf(2.f * a.w - ri[3] - rj);
        }
    }
    #pragma unroll
    for (int o = 32; o; o >>= 1) psum += __shfl_xor(psum, o, 64);
    if (lane == 0) wsum[wv] = psum;
    __syncthreads();
    if (tid == 0) {
        float bs = wsum[0] + wsum[1] + wsum[2] + wsum[3];
        double sgn = ((I < 32) == (J < 32)) ? 1.0 : -1.0;
        double fac = (I == J) ? 1.0 : 2.0;
        blocksum[blockIdx.x] = sgn * fac * (double)bs;
    }
}

// ---------------- K6: finalize (reduce 2080 block sums) ----------------------
__global__ __launch_bounds__(256) void k_final(
    const double* __restrict__ blocksum, float* __restrict__ out) {
    __shared__ double sh[4];
    int t = threadIdx.x, wv = t >> 6, lane = t & 63;
    double s = 0.0;
    for (int i = t; i < NTRI; i += 256) s += blocksum[i];
    #pragma unroll
    for (int o = 32; o; o >>= 1) s += __shfl_xor(s, o, 64);
    if (lane == 0) sh[wv] = s;
    __syncthreads();
    if (t == 0) {
        double tot = sh[0] + sh[1] + sh[2] + sh[3];
        out[0] = (float)(tot / ((double)B_ROWS * (double)B_ROWS));
    }
}

extern "C" void kernel_launch(void* const* d_in, const int* in_sizes, int n_in,
                              void* d_out, int out_size, void* d_ws, size_t ws_size,
                              hipStream_t stream) {
    const float* s0 = (const float*)d_in[0];
    const float* s1 = (const float*)d_in[1];
    const float* t0 = (const float*)d_in[2];
    const float* t1 = (const float*)d_in[3];
    char* ws = (char*)d_ws;
    float*  gam  = (float*)(ws + OFF_GAM);
    float*  sq0  = (float*)(ws + OFF_SQ0);
    float*  sq1  = (float*)(ws + OFF_SQ1);
    float*  rvec = (float*)(ws + OFF_R);
    float*  p0   = (float*)(ws + OFF_P0);
    float*  p1   = (float*)(ws + OFF_P1);
    double* bsum = (double*)(ws + OFF_BSUM);
    unsigned char* phi = (unsigned char*)(ws + OFF_PHI);

    k_rowsq<<<2048, 256, 0, stream>>>(s0, s1, t0, t1, sq0, sq1);
    k_colsum<<<NCB, 256, 0, stream>>>(s0, s1, t0, t1, p0, p1);
    k_gamma<<<1, 256, 0, stream>>>(sq0, sq1, p0, p1, gam);
    k_pack<<<2048, 256, 0, stream>>>(s0, s1, t0, t1, gam, phi, rvec);
    k_mmd<<<NTRI, 256, 0, stream>>>(phi, rvec, bsum);
    k_final<<<1, 256, 0, stream>>>(bsum, (float*)d_out);
}